// Round 5
// baseline (81.704 us; speedup 1.0000x reference)
//
#include <hip/hip_runtime.h>
#include <hip/hip_bf16.h>
#include <math.h>

#define NN 60000
#define D 300
#define R 5
#define NE 1000000
#define B 32
#define NG 25000
#define NS 25000
#define NROWS 50000
#define HCP 304        // hc row padded to 304 (19 * 16)
#define NBLK 1563      // head_gemm blocks = ceil(50000/32)

typedef __bf16 bf16x8 __attribute__((ext_vector_type(8)));
typedef float f32x16 __attribute__((ext_vector_type(16)));

// ws layout (floats):
//   wsum [0, 48000)          f32 accum of x[src] per (b,r)
//   wcnt [48000, 48160)      f32 counts
//   hcf  [48160, 57760)      f32 hc accumulator (atomic)
//   done [57760]             int, rgcn_hc last-block counter
//   pad  [57761, 57764)
//   hcb  [57764, 62628)      bf16 32x304 (16B aligned: 57764*4 % 16 == 0)
//   pm2  [62628, 262756)     float2 [64 rows][1563 blocks] (m, s) partials

__global__ void zero_ws(float4* __restrict__ p) {
    int i = blockIdx.x * 256 + threadIdx.x;
    if (i < 14441) p[i] = float4{0.f, 0.f, 0.f, 0.f};  // [0, 57764) floats
}

// Fused scan + accumulate: bloom-filter dst, compact matches into LDS, then the
// whole block does coalesced 300-float atomic row-adds per match.
__global__ __launch_bounds__(256) void scan_accum(
        const int* __restrict__ ei, const int* __restrict__ et,
        const int* __restrict__ cur, const float* __restrict__ x,
        float* __restrict__ wsum, float* __restrict__ wcnt) {
    __shared__ unsigned int tbl[32];
    __shared__ int curl[B];
    __shared__ int lcnt;
    __shared__ int2 loc[64];
    int tid = threadIdx.x;
    if (tid < 32) tbl[tid] = 0u;
    if (tid == 0) lcnt = 0;
    __syncthreads();
    if (tid < B) {
        int c = cur[tid];
        curl[tid] = c;
        atomicOr(&tbl[(c >> 5) & 31], 1u << (c & 31));
    }
    __syncthreads();
    long base = ((long)blockIdx.x * 256 + tid) * 4;
    if (base < NE) {
        int ds[4];
        if (base + 4 <= NE) {
            int4 d4 = *(const int4*)(ei + NE + base);
            ds[0] = d4.x; ds[1] = d4.y; ds[2] = d4.z; ds[3] = d4.w;
        } else {
            for (int k = 0; k < 4; ++k) ds[k] = (base + k < NE) ? ei[NE + base + k] : -1;
        }
        #pragma unroll
        for (int k = 0; k < 4; ++k) {
            int dst = ds[k];
            if (dst < 0) continue;
            if (!(tbl[(dst >> 5) & 31] & (1u << (dst & 31)))) continue;  // bloom reject
            int e = (int)base + k;
            int r = -1, s = 0;
            for (int b = 0; b < B; ++b) {
                if (dst == curl[b]) {
                    if (r < 0) { r = et[e]; s = ei[e]; }
                    int slot = b * R + r;
                    atomicAdd(&wcnt[slot], 1.0f);
                    int p = atomicAdd(&lcnt, 1);
                    if (p < 64) loc[p] = int2{s, slot};
                }
            }
        }
    }
    __syncthreads();
    int n = lcnt; if (n > 64) n = 64;
    for (int m = 0; m < n; ++m) {
        int2 pr = loc[m];
        const float* xs = x + (long)pr.x * D;
        float* sm = wsum + (long)pr.y * D;
        for (int t = tid; t < D; t += 256) atomicAdd(&sm[t], xs[t]);
    }
}

// Fused RGCN transform: 36 blocks, each computes its 50-row K-chunk of
// U[32x1800] @ M[1800x300] inline (U built from x / wsum / comp on the fly),
// atomic-accumulates into hcf; last block applies bias+relu -> bf16 hcb.
__global__ __launch_bounds__(320) void rgcn_hc(
        const float* __restrict__ x, const int* __restrict__ cur,
        const float* __restrict__ comp, const float* __restrict__ root,
        const float* __restrict__ basis, const float* __restrict__ bias,
        const float* __restrict__ wsum, const float* __restrict__ wcnt,
        float* __restrict__ hcf, int* __restrict__ done, __bf16* __restrict__ hcb) {
    int kc = blockIdx.x, t = threadIdx.x;
    __shared__ float uL[B * 50];
    __shared__ float cmp[R * R];
    __shared__ float inv[B * R];
    __shared__ int curlS[B];
    __shared__ int lastFlag;
    if (t < R * R) cmp[t] = comp[t];
    if (t < B * R) inv[t] = 1.0f / fmaxf(wcnt[t], 1.0f);
    if (t < B) curlS[t] = cur[t];
    __syncthreads();
    int d0 = kc * 50;
    if (kc < 6) {
        for (int i = t; i < B * 50; i += 320) {
            int b = i / 50, dd = i - b * 50;
            uL[i] = x[(long)curlS[b] * D + d0 + dd];
        }
    } else {
        int g0 = d0 - 300;
        int bb = g0 / 300, t0 = g0 - bb * 300;
        for (int i = t; i < B * 50; i += 320) {
            int b = i / 50, dd = i - b * 50;
            float a = 0.f;
            #pragma unroll
            for (int r = 0; r < R; ++r)
                a = fmaf(cmp[r * R + bb] * inv[b * R + r], wsum[((long)b * R + r) * D + t0 + dd], a);
            uL[i] = a;
        }
    }
    __syncthreads();
    const float* Mb = (kc < 6) ? (root + (long)d0 * D) : (basis + (long)(d0 - 300) * D);
    if (t < D) {
        float acc[B] = {};
        #pragma unroll 5
        for (int i = 0; i < 50; ++i) {
            float m = Mb[(long)i * D + t];
            #pragma unroll
            for (int b = 0; b < B; ++b) acc[b] = fmaf(uL[b * 50 + i], m, acc[b]);
        }
        for (int b = 0; b < B; ++b) atomicAdd(&hcf[b * D + t], acc[b]);
    }
    __syncthreads();
    if (t == 0) {
        __threadfence();
        int p = atomicAdd(done, 1);
        lastFlag = (p == 35);
    }
    __syncthreads();
    if (!lastFlag) return;
    __threadfence();
    for (int i = t; i < B * HCP; i += 320) {
        int b = i / HCP, tt = i - b * HCP;
        float a = 0.f;
        if (tt < D) {
            a = atomicAdd(&hcf[b * D + tt], 0.0f) + bias[tt];  // coherent read
            a = fmaxf(a, 0.f);
        }
        hcb[i] = (__bf16)a;
    }
}

__device__ inline void online_upd(float& m, float& s, float v) {
    if (v > m) { s = s * __expf(m - v) + 1.0f; m = v; }
    else       { s += __expf(v - m); }
}
__device__ inline void online_merge(float& m, float& s, float om, float os) {
    float M = fmaxf(m, om);
    s = s * __expf(m - M) + os * __expf(om - M);
    m = M;
}

// MFMA head GEMM: one wave = 32j x 32b tile, K=300 (19 steps of 16).
// Epilogue: per-(head,b) online (max, sum-exp) partials -> pm2[row][blk].
__global__ __launch_bounds__(64) void head_gemm_mfma(
    const __bf16* __restrict__ hcb, const float* __restrict__ wg, const float* __restrict__ bg,
    const float* __restrict__ wsn, const float* __restrict__ bsn,
    float* __restrict__ out, float2* __restrict__ pm2) {
    int l = threadIdx.x;
    int j0 = blockIdx.x * 32;
    int lm = l & 31, lh = l >> 5;

    bf16x8 bfrag[19];
    const __bf16* hrow = hcb + lm * HCP + lh * 8;
    #pragma unroll
    for (int s = 0; s < 19; ++s) bfrag[s] = *(const bf16x8*)(hrow + 16 * s);

    int row = j0 + lm; if (row >= NROWS) row = NROWS - 1;
    const float* wrow = ((row < NG) ? (wg + (long)row * D) : (wsn + (long)(row - NG) * D)) + lh * 8;

    f32x16 acc = {};
    #pragma unroll
    for (int s = 0; s < 18; ++s) {
        float4 w0 = *(const float4*)(wrow + 16 * s);
        float4 w1 = *(const float4*)(wrow + 16 * s + 4);
        bf16x8 a;
        a[0] = (__bf16)w0.x; a[1] = (__bf16)w0.y; a[2] = (__bf16)w0.z; a[3] = (__bf16)w0.w;
        a[4] = (__bf16)w1.x; a[5] = (__bf16)w1.y; a[6] = (__bf16)w1.z; a[7] = (__bf16)w1.w;
        acc = __builtin_amdgcn_mfma_f32_32x32x16_bf16(a, bfrag[s], acc, 0, 0, 0);
    }
    {
        float4 w0, w1;
        if (lh == 0) {
            w0 = *(const float4*)(wrow + 288);
            w1 = *(const float4*)(wrow + 292);
        } else {
            w0 = *(const float4*)(wrow + 288);  // = row base + 296
            w1 = float4{0.f, 0.f, 0.f, 0.f};
        }
        bf16x8 a;
        a[0] = (__bf16)w0.x; a[1] = (__bf16)w0.y; a[2] = (__bf16)w0.z; a[3] = (__bf16)w0.w;
        a[4] = (__bf16)w1.x; a[5] = (__bf16)w1.y; a[6] = (__bf16)w1.z; a[7] = (__bf16)w1.w;
        acc = __builtin_amdgcn_mfma_f32_32x32x16_bf16(a, bfrag[18], acc, 0, 0, 0);
    }

    int b = lm;
    float m0 = -3.0e38f, s0 = 0.f, m1 = -3.0e38f, s1 = 0.f;
    #pragma unroll
    for (int r = 0; r < 16; ++r) {
        int j = j0 + (r & 3) + 8 * (r >> 2) + 4 * lh;
        if (j >= NROWS) continue;
        float bv = (j < NG) ? bg[j] : bsn[j - NG];
        float v = acc[r] + bv;
        float* op = (j < NG) ? (out + (long)b * NG + j)
                             : (out + (long)B * NG + (long)b * NS + (j - NG));
        *op = v;
        if (j < NG) online_upd(m0, s0, v); else online_upd(m1, s1, v);
    }
    // merge the two lanes (lh=0/1) that share b, then lane lh==0 writes partials
    float om0 = __shfl_xor(m0, 32), os0 = __shfl_xor(s0, 32);
    float om1 = __shfl_xor(m1, 32), os1 = __shfl_xor(s1, 32);
    online_merge(m0, s0, om0, os0);
    online_merge(m1, s1, om1, os1);
    if (lh == 0) {
        pm2[(long)b * NBLK + blockIdx.x]       = float2{m0, s0};
        pm2[(long)(B + b) * NBLK + blockIdx.x] = float2{m1, s1};
    }
}

// 1600 blocks: each reduces its row's pm2 strip (L2-hot, 12.5 KB) to lse,
// then subtracts over its 250-float4 chunk of the row.
__global__ __launch_bounds__(256) void sub_lse(float* __restrict__ out,
                                               const float2* __restrict__ pm2) {
    int row = blockIdx.x / 25, c = blockIdx.x % 25;
    int tid = threadIdx.x;
    const float2* pr = pm2 + (long)row * NBLK;
    float m = -3.0e38f, s = 0.f;
    for (int i = tid; i < NBLK; i += 256) {
        float2 e = pr[i];
        online_merge(m, s, e.x, e.y);
    }
    #pragma unroll
    for (int o = 32; o; o >>= 1) {
        float om = __shfl_xor(m, o), os = __shfl_xor(s, o);
        online_merge(m, s, om, os);
    }
    __shared__ float sm[4], ss[4];
    __shared__ float lseS;
    if ((tid & 63) == 0) { sm[tid >> 6] = m; ss[tid >> 6] = s; }
    __syncthreads();
    if (tid == 0) {
        float M = sm[0], S = ss[0];
        for (int w = 1; w < 4; ++w) online_merge(M, S, sm[w], ss[w]);
        lseS = M + __logf(S);
    }
    __syncthreads();
    float lse = lseS;
    float4* o4 = (float4*)out + (long)row * 6250 + c * 250;
    if (tid < 250) {
        float4 v = o4[tid];
        v.x -= lse; v.y -= lse; v.z -= lse; v.w -= lse;
        o4[tid] = v;
    }
}

extern "C" void kernel_launch(void* const* d_in, const int* in_sizes, int n_in,
                              void* d_out, int out_size, void* d_ws, size_t ws_size,
                              hipStream_t stream) {
    const float* x     = (const float*)d_in[0];
    const int*   ei    = (const int*)d_in[1];
    const int*   et    = (const int*)d_in[2];
    const int*   cur   = (const int*)d_in[3];
    const float* basis = (const float*)d_in[4];
    const float* comp  = (const float*)d_in[5];
    const float* root  = (const float*)d_in[6];
    const float* bias  = (const float*)d_in[7];
    const float* wg    = (const float*)d_in[8];
    const float* bgl   = (const float*)d_in[9];
    const float* wsn   = (const float*)d_in[10];
    const float* bsn   = (const float*)d_in[11];
    float* out  = (float*)d_out;
    float* wsf  = (float*)d_ws;
    float* wsum  = wsf;                          // [0, 48000)
    float* wcnt  = wsf + 48000;                  // [48000, 48160)
    float* hcf   = wsf + 48160;                  // [48160, 57760)
    int*   done  = (int*)(wsf + 57760);          // 1 int
    __bf16* hcb  = (__bf16*)(wsf + 57764);       // 32*304 bf16
    float2* pm2  = (float2*)(wsf + 62628);       // 64 x 1563 float2

    zero_ws<<<57, 256, 0, stream>>>((float4*)d_ws);
    scan_accum<<<977, 256, 0, stream>>>(ei, et, cur, x, wsum, wcnt);
    rgcn_hc<<<36, 320, 0, stream>>>(x, cur, comp, root, basis, bias, wsum, wcnt, hcf, done, hcb);
    head_gemm_mfma<<<NBLK, 64, 0, stream>>>(hcb, wg, bgl, wsn, bsn, out, pm2);
    sub_lse<<<1600, 256, 0, stream>>>(out, pm2);
}